// Round 1
// baseline (656.849 us; speedup 1.0000x reference)
//
#include <hip/hip_runtime.h>

#define TLEN 4096
#define NBK  32

typedef __attribute__((ext_vector_type(8))) short short8;
typedef __attribute__((ext_vector_type(8))) unsigned short ushort8;
typedef __attribute__((ext_vector_type(4))) float f32x4;

// workspace float offsets
#define OFF_WC 0        // 1160*3
#define OFF_BC 3480     // 1160
#define OFF_W3 4640     // 640*12  folded conv*proj weights
#define OFF_TB 12320    // 640*4   per-tap bias (for causal pad masking)
#define OFF_NW 14880    // 512     norm_w * colsum(out_proj_w)
#define OFF_Y_BYTES 262144   // bf16 Y buffer: 32*4096*512 ushort = 134.2 MB

__device__ __forceinline__ unsigned short f2bf(float f){
  unsigned int u = __float_as_uint(f);
  u = (u + 0x7FFFu + ((u >> 16) & 1u)) >> 16;
  return (unsigned short)u;
}
__device__ __forceinline__ float bf2f(unsigned short h){
  return __uint_as_float(((unsigned int)h) << 16);
}
__device__ __forceinline__ float softplusf_(float x){
  return (x > 15.f) ? x : log1pf(__expf(x));
}
__device__ __forceinline__ float siluf_(float x){
  return x / (1.f + __expf(-x));
}

// ---- prep 1: Wc = in_proj_w @ W_in (1160x3), biasc = in_proj_w @ b_in ----
__global__ void prep1_kernel(const float* __restrict__ ipw,
                             const float* __restrict__ W_in,
                             const float* __restrict__ b_in,
                             float* __restrict__ wsf){
  int r = blockIdx.x*256 + threadIdx.x;
  if (r >= 1160) return;
  const float* row = ipw + (size_t)r*256;
  float a0=0.f,a1=0.f,a2=0.f,ab=0.f;
  for (int m=0;m<256;m++){
    float w = row[m];
    a0 = fmaf(w, W_in[m*3+0], a0);
    a1 = fmaf(w, W_in[m*3+1], a1);
    a2 = fmaf(w, W_in[m*3+2], a2);
    ab = fmaf(w, b_in[m], ab);
  }
  wsf[OFF_WC + r*3+0]=a0; wsf[OFF_WC + r*3+1]=a1; wsf[OFF_WC + r*3+2]=a2;
  wsf[OFF_BC + r]=ab;
}

// ---- prep 2: folded conv tables + nw = norm_w * colsum(out_proj_w) ----
__global__ void prep2_kernel(const float* __restrict__ conv_w,
                             const float* __restrict__ norm_w,
                             const float* __restrict__ out_proj_w,
                             float* __restrict__ wsf){
  int r = blockIdx.x*256 + threadIdx.x;
  if (r < 640){
    float bc = wsf[OFF_BC + 512 + r];
    #pragma unroll
    for (int i=0;i<4;i++){
      float cw = conv_w[r*4+i];
      wsf[OFF_TB + r*4+i] = cw*bc;
      wsf[OFF_W3 + r*12 + i*3+0] = cw * wsf[OFF_WC + (512+r)*3+0];
      wsf[OFF_W3 + r*12 + i*3+1] = cw * wsf[OFF_WC + (512+r)*3+1];
      wsf[OFF_W3 + r*12 + i*3+2] = cw * wsf[OFF_WC + (512+r)*3+2];
    }
  }
  if (r < 512){
    float s=0.f;
    for (int m=0;m<256;m++) s += out_proj_w[(size_t)m*512 + r];
    wsf[OFF_NW + r] = norm_w[r]*s;
  }
}

// ---- SSD: one block per (b,h); state lives in regs across the 64-chunk loop ----
__global__ __launch_bounds__(1024, 1) void ssd_kernel(
    const float* __restrict__ obs, const float* __restrict__ conv_b,
    const float* __restrict__ dt_bias, const float* __restrict__ A_log,
    const float* __restrict__ D_param, const float* __restrict__ wsf,
    unsigned short* __restrict__ Yg)
{
  __shared__ float obs_s[67*3];
  __shared__ float W3l[192*12];
  __shared__ float tbl[192*4];
  __shared__ float cbl[192];
  // stride 72 ushorts (144B rows: 16B-aligned, 2-way-at-worst on b128 reads)
  __shared__ unsigned short Bs[64*72], BDTl[64*72], Cs[64*72], CEl[64*72],
                            XDT[64*72], XSl[64*72], Mm[64*72], Sb[64*72];

  const int tid  = threadIdx.x;
  const int b    = blockIdx.x >> 3;
  const int h    = blockIdx.x & 7;
  const int lane = tid & 63;
  const int wid  = tid >> 6;          // 0..15
  const int tm   = wid >> 2, tn = wid & 3;

  // stage per-head channel tables: lc<64 -> conv ch h*64+lc (xs), else 448+lc (B,C)
  for (int i = tid; i < 192*12; i += 1024){
    int lc = i/12; int ch = (lc<64) ? h*64+lc : 448+lc;
    W3l[i] = wsf[OFF_W3 + ch*12 + (i - lc*12)];
  }
  for (int i = tid; i < 192*4; i += 1024){
    int lc = i>>2; int ch = (lc<64) ? h*64+lc : 448+lc;
    tbl[i] = wsf[OFF_TB + ch*4 + (i&3)];
  }
  for (int i = tid; i < 192; i += 1024){
    int ch = (i<64)? h*64+i : 448+i;
    cbl[i] = conv_b[ch];
  }
  const float Wd0 = wsf[OFF_WC+(1152+h)*3+0], Wd1 = wsf[OFF_WC+(1152+h)*3+1], Wd2 = wsf[OFF_WC+(1152+h)*3+2];
  const float bdt = wsf[OFF_BC + 1152 + h] + dt_bias[h];
  const float A_h = -__expf(A_log[h]);
  const float Dh  = D_param[h];

  f32x4 sreg = {0.f,0.f,0.f,0.f};          // state S^T tile (rows n=tm, cols p=tn)

  const int am    = tm*16 + (lane & 15);   // A-operand row index
  const int bn    = tn*16 + (lane & 15);   // B-operand row index (= D col)
  const int rbase = tm*16 + ((lane>>4)&3)*4;  // D row base

  __syncthreads();

  for (int c = 0; c < 64; ++c){
    const int t0 = c*64;
    // ---------- phase A: obs window, Sb <- sreg, dt/cumsum ----------
    for (int i = tid; i < 67*3; i += 1024){
      int rw = i/3, j = i - rw*3;
      int tt = t0 - 3 + rw;
      obs_s[i] = (tt >= 0) ? obs[(size_t)tt*(NBK*3) + b*3 + j] : 0.f;
    }
    #pragma unroll
    for (int r=0;r<4;r++)
      Sb[bn*72 + rbase + r] = f2bf(sreg[r]);   // Sb[p][n] = S entering chunk

    float dtv, acsv, eAv, dcyv, eAtot;
    {
      int tt = t0 + lane;
      const float* ob = obs + (size_t)tt*(NBK*3) + b*3;
      float draw = bdt + Wd0*ob[0] + Wd1*ob[1] + Wd2*ob[2];
      dtv = softplusf_(draw);
      float acs = A_h * dtv;
      #pragma unroll
      for (int o=1;o<64;o<<=1){            // inclusive scan
        float u = __shfl_up(acs, o);
        if (lane >= o) acs += u;
      }
      acsv = acs;
      float At = __shfl(acsv, 63);
      eAv   = __expf(acsv);
      dcyv  = __expf(At - acsv);
      eAtot = __expf(At);
    }
    __syncthreads();

    // ---------- phase C: staging (lane = l, wave owns 12 channels) ----------
    {
      const int l = lane;
      float o[4][3];
      #pragma unroll
      for (int i=0;i<4;i++){
        o[i][0]=obs_s[(l+i)*3+0]; o[i][1]=obs_s[(l+i)*3+1]; o[i][2]=obs_s[(l+i)*3+2];
      }
      float vm[4];
      #pragma unroll
      for (int i=0;i<4;i++) vm[i] = (t0 + l - 3 + i >= 0) ? 1.f : 0.f;
      #pragma unroll
      for (int qq=0; qq<12; qq++){
        int lc = wid*12 + qq;              // broadcast LDS reads across the wave
        const float* w = &W3l[lc*12];
        float pre = cbl[lc];
        #pragma unroll
        for (int i=0;i<4;i++){
          pre += vm[i]*tbl[lc*4+i];
          pre = fmaf(o[i][0], w[i*3+0], pre);
          pre = fmaf(o[i][1], w[i*3+1], pre);
          pre = fmaf(o[i][2], w[i*3+2], pre);
        }
        float v = siluf_(pre);
        if (lc < 64){
          XSl[l*72+lc] = f2bf(v);
          XDT[lc*72+l] = f2bf(v*dtv);        // xdt^T [p][s]
        } else if (lc < 128){
          int n = lc-64;
          Bs[l*72+n]   = f2bf(v);            // B [s][n]
          BDTl[n*72+l] = f2bf(v*dcyv);       // (B*decay)^T [n][s]
        } else {
          int n = lc-128;
          Cs[l*72+n]  = f2bf(v);             // C [l][n]
          CEl[l*72+n] = f2bf(v*eAv);         // C*exp(Acs) [l][n]
        }
      }
    }
    __syncthreads();

    // ---------- phase D: G = C·B^T, M = G ∘ L ----------
    {
      f32x4 g = {0.f,0.f,0.f,0.f};
      #pragma unroll
      for (int k=0;k<2;k++){
        int kb = k*32 + ((lane>>4)&3)*8;
        short8 av = *(const short8*)&Cs[am*72 + kb];
        short8 bv = *(const short8*)&Bs[bn*72 + kb];
        g = __builtin_amdgcn_mfma_f32_16x16x32_bf16(av, bv, g, 0, 0, 0);
      }
      #pragma unroll
      for (int r=0;r<4;r++){
        int lrow = rbase + r;
        float acl = __shfl(acsv, lrow);
        float acS = __shfl(acsv, bn);
        float mval = (lrow >= bn) ? g[r]*__expf(acl - acS) : 0.f;
        Mm[lrow*72 + bn] = f2bf(mval);
      }
    }
    __syncthreads();

    // ---------- phase E: Y = M·xdt + CE·S^T (+ xs*D), state update ----------
    {
      f32x4 y = {0.f,0.f,0.f,0.f};
      #pragma unroll
      for (int k=0;k<2;k++){
        int kb = k*32 + ((lane>>4)&3)*8;
        short8 av = *(const short8*)&Mm[am*72 + kb];
        short8 bv = *(const short8*)&XDT[bn*72 + kb];
        y = __builtin_amdgcn_mfma_f32_16x16x32_bf16(av, bv, y, 0, 0, 0);
      }
      #pragma unroll
      for (int k=0;k<2;k++){
        int kb = k*32 + ((lane>>4)&3)*8;
        short8 av = *(const short8*)&CEl[am*72 + kb];
        short8 bv = *(const short8*)&Sb[bn*72 + kb];
        y = __builtin_amdgcn_mfma_f32_16x16x32_bf16(av, bv, y, 0, 0, 0);
      }
      #pragma unroll
      for (int r=0;r<4;r++) sreg[r] *= eAtot;
      #pragma unroll
      for (int k=0;k<2;k++){
        int kb = k*32 + ((lane>>4)&3)*8;
        short8 av = *(const short8*)&BDTl[am*72 + kb];
        short8 bv = *(const short8*)&XDT[bn*72 + kb];
        sreg = __builtin_amdgcn_mfma_f32_16x16x32_bf16(av, bv, sreg, 0, 0, 0);
      }
      #pragma unroll
      for (int r=0;r<4;r++){
        int lrow = rbase + r;
        float xsv = bf2f(XSl[lrow*72 + bn]);
        float yo = y[r] + xsv*Dh;
        Yg[((size_t)(b*4096 + t0 + lrow))*512 + h*64 + bn] = f2bf(yo);
      }
    }
    __syncthreads();
  }
}

// ---- final: gate with silu(z), RMSNorm, folded out-proj dot, q & logits ----
__global__ __launch_bounds__(256) void final_kernel(
    const unsigned short* __restrict__ Yg, const float* __restrict__ obs,
    const float* __restrict__ wsf, const float* __restrict__ head,
    const float* __restrict__ log_tau, float* __restrict__ out)
{
  __shared__ float Wz[512*3];
  __shared__ float bz[512];
  __shared__ float nwl[512];
  int tid = threadIdx.x;
  for (int i=tid; i<512*3; i+=256) Wz[i] = wsf[OFF_WC + i];
  for (int i=tid; i<512; i+=256){ bz[i] = wsf[OFF_BC+i]; nwl[i] = wsf[OFF_NW+i]; }
  __syncthreads();
  int wid = tid>>6, lane = tid&63;
  int row = blockIdx.x*4 + wid;          // b*4096 + t
  int bb = row >> 12, t = row & 4095;
  const float* ob = obs + (size_t)t*(NBK*3) + bb*3;
  float o0=ob[0], o1=ob[1], o2=ob[2];
  ushort8 yv = *(const ushort8*)&Yg[(size_t)row*512 + lane*8];
  float s2=0.f, sq=0.f;
  #pragma unroll
  for (int u=0;u<8;u++){
    int i = lane*8+u;
    float yf = bf2f(yv[u]);
    float z = bz[i] + Wz[i*3]*o0 + Wz[i*3+1]*o1 + Wz[i*3+2]*o2;
    float yg = yf * siluf_(z);
    s2 = fmaf(yg, yg, s2);
    sq = fmaf(yg, nwl[i], sq);
  }
  #pragma unroll
  for (int o=32;o;o>>=1){ s2 += __shfl_xor(s2,o); sq += __shfl_xor(sq,o); }
  if (lane==0){
    float rms = rsqrtf(s2*(1.f/512.f) + 1e-5f);
    float q = sq * rms * softplusf_(head[0]);
    out[(size_t)t*32 + bb] = q;
    out[131072 + (size_t)t*32 + bb] = q * __expf(-log_tau[0]);
  }
}

extern "C" void kernel_launch(void* const* d_in, const int* in_sizes, int n_in,
                              void* d_out, int out_size, void* d_ws, size_t ws_size,
                              hipStream_t stream) {
  (void)in_sizes; (void)n_in; (void)out_size; (void)ws_size;
  const float* obs        = (const float*)d_in[0];
  const float* W_in       = (const float*)d_in[1];
  const float* b_in       = (const float*)d_in[2];
  const float* in_proj_w  = (const float*)d_in[3];
  const float* conv_w     = (const float*)d_in[4];
  const float* conv_b     = (const float*)d_in[5];
  const float* dt_bias    = (const float*)d_in[6];
  const float* A_log      = (const float*)d_in[7];
  const float* D_param    = (const float*)d_in[8];
  const float* norm_w     = (const float*)d_in[9];
  const float* out_proj_w = (const float*)d_in[10];
  const float* head       = (const float*)d_in[11];
  const float* log_tau    = (const float*)d_in[12];
  float* wsf = (float*)d_ws;
  unsigned short* Yg = (unsigned short*)((char*)d_ws + OFF_Y_BYTES);
  float* out = (float*)d_out;

  prep1_kernel<<<5, 256, 0, stream>>>(in_proj_w, W_in, b_in, wsf);
  prep2_kernel<<<3, 256, 0, stream>>>(conv_w, norm_w, out_proj_w, wsf);
  ssd_kernel<<<256, 1024, 0, stream>>>(obs, conv_b, dt_bias, A_log, D_param, wsf, Yg);
  final_kernel<<<32768, 256, 0, stream>>>(Yg, obs, wsf, head, log_tau, out);
}

// Round 2
// 456.724 us; speedup vs baseline: 1.4382x; 1.4382x over previous
//
#include <hip/hip_runtime.h>

#define TLEN 4096
#define NBK  32

typedef __attribute__((ext_vector_type(8))) short short8;
typedef __attribute__((ext_vector_type(8))) unsigned short ushort8;
typedef __attribute__((ext_vector_type(4))) unsigned short ushort4v;
typedef __attribute__((ext_vector_type(4))) float f32x4;

// workspace float offsets
#define OFF_WC 0        // 1160*3
#define OFF_BC 3480     // 1160
#define OFF_W3 4640     // 640*12  folded conv*proj weights
#define OFF_TB 12320    // 640*4   per-tap bias (for causal pad masking)
#define OFF_NW 14880    // 512     norm_w * colsum(out_proj_w)
#define OFF_Y_BYTES 262144   // bf16 Y buffer: 32*4096*512 ushort = 134.2 MB

__device__ __forceinline__ unsigned short f2bf(float f){
  unsigned int u = __float_as_uint(f);
  u = (u + 0x7FFFu + ((u >> 16) & 1u)) >> 16;
  return (unsigned short)u;
}
__device__ __forceinline__ float bf2f(unsigned short h){
  return __uint_as_float(((unsigned int)h) << 16);
}
__device__ __forceinline__ float softplusf_(float x){
  return (x > 15.f) ? x : log1pf(__expf(x));
}
__device__ __forceinline__ float siluf_(float x){
  return x * __fdividef(1.f, 1.f + __expf(-x));
}

// ---- prep 1: Wc = in_proj_w @ W_in (1160x3), biasc = in_proj_w @ b_in ----
__global__ void prep1_kernel(const float* __restrict__ ipw,
                             const float* __restrict__ W_in,
                             const float* __restrict__ b_in,
                             float* __restrict__ wsf){
  int r = blockIdx.x*256 + threadIdx.x;
  if (r >= 1160) return;
  const float* row = ipw + (size_t)r*256;
  float a0=0.f,a1=0.f,a2=0.f,ab=0.f;
  for (int m=0;m<256;m++){
    float w = row[m];
    a0 = fmaf(w, W_in[m*3+0], a0);
    a1 = fmaf(w, W_in[m*3+1], a1);
    a2 = fmaf(w, W_in[m*3+2], a2);
    ab = fmaf(w, b_in[m], ab);
  }
  wsf[OFF_WC + r*3+0]=a0; wsf[OFF_WC + r*3+1]=a1; wsf[OFF_WC + r*3+2]=a2;
  wsf[OFF_BC + r]=ab;
}

// ---- prep 2: folded conv tables + nw = norm_w * colsum(out_proj_w) ----
__global__ void prep2_kernel(const float* __restrict__ conv_w,
                             const float* __restrict__ norm_w,
                             const float* __restrict__ out_proj_w,
                             float* __restrict__ wsf){
  int r = blockIdx.x*256 + threadIdx.x;
  if (r < 640){
    float bc = wsf[OFF_BC + 512 + r];
    #pragma unroll
    for (int i=0;i<4;i++){
      float cw = conv_w[r*4+i];
      wsf[OFF_TB + r*4+i] = cw*bc;
      wsf[OFF_W3 + r*12 + i*3+0] = cw * wsf[OFF_WC + (512+r)*3+0];
      wsf[OFF_W3 + r*12 + i*3+1] = cw * wsf[OFF_WC + (512+r)*3+1];
      wsf[OFF_W3 + r*12 + i*3+2] = cw * wsf[OFF_WC + (512+r)*3+2];
    }
  }
  if (r < 512){
    float s=0.f;
    for (int m=0;m<256;m++) s += out_proj_w[(size_t)m*512 + r];
    wsf[OFF_NW + r] = norm_w[r]*s;
  }
}

// swizzled index into a [64][64] ushort tile: col ^= (row&7)<<3
#define SW(row_, col_) ((row_)*64 + ((col_) ^ (((row_)&7)<<3)))

// ---- SSD: one block per (b,h); state in regs across the 64-chunk loop ----
__global__ __launch_bounds__(1024, 1) void ssd_kernel(
    const float* __restrict__ obs, const float* __restrict__ conv_b,
    const float* __restrict__ dt_bias, const float* __restrict__ A_log,
    const float* __restrict__ D_param, const float* __restrict__ wsf,
    unsigned short* __restrict__ Yg)
{
  __shared__ __align__(16) unsigned short obs_b[3*4096];   // [j][t] bf16
  __shared__ __align__(16) unsigned short W3T[192*40];     // conv-GEMM A (static, K pad 12->32)
  __shared__ __align__(16) unsigned short OW[2][64*40];    // conv-GEMM B (per-chunk, dbuf)
  __shared__ float dt_l[4096];
  __shared__ float acs_l[4096];
  __shared__ float CBe[192];
  __shared__ float TBl[192*4];
  __shared__ __align__(16) unsigned short Bs[64*64], BDTl[64*64], Cs[64*64],
      CEl[64*64], XDT[64*64], XSl[64*64], Mm[64*64], Sb[64*64];

  const int tid  = threadIdx.x;
  const int b    = blockIdx.x >> 3;
  const int h    = blockIdx.x & 7;
  const int lane = tid & 63;
  const int wid  = tid >> 6;          // 0..15
  const int tm   = wid >> 2, tn = wid & 3;

  const int am    = tm*16 + (lane & 15);
  const int bn    = tn*16 + (lane & 15);
  const int rbase = tm*16 + ((lane>>4)&3)*4;

  // ---------------- prologue part 1: stage static LDS ----------------
  for (int idx = tid; idx < 3*4096; idx += 1024){
    int j = idx >> 12, t = idx & 4095;
    obs_b[idx] = f2bf(obs[(size_t)t*(NBK*3) + b*3 + j]);
  }
  // zero pad columns 12..39 of W3T and both OW buffers
  for (int idx = tid; idx < 192*28; idx += 1024){
    int row = idx/28; W3T[row*40 + 12 + (idx - row*28)] = 0;
  }
  for (int idx = tid; idx < 2*64*28; idx += 1024){
    int row = idx/28; (&OW[0][0])[row*40 + 12 + (idx - row*28)] = 0;
  }
  for (int idx = tid; idx < 192*12; idx += 1024){
    int lc = idx/12, ij = idx - lc*12;
    int ch = (lc<64) ? h*64+lc : 448+lc;
    W3T[lc*40 + ij] = f2bf(wsf[OFF_W3 + ch*12 + ij]);
  }
  for (int idx = tid; idx < 192; idx += 1024){
    int ch = (idx<64) ? h*64+idx : 448+idx;
    float s = conv_b[ch];
    #pragma unroll
    for (int i=0;i<4;i++){ float tb = wsf[OFF_TB + ch*4 + i]; TBl[idx*4+i] = tb; s += tb; }
    CBe[idx] = s;
  }
  // dt + chunk-local A-cumsum arrays (f32, from global obs)
  const float Wd0 = wsf[OFF_WC+(1152+h)*3+0], Wd1 = wsf[OFF_WC+(1152+h)*3+1],
              Wd2 = wsf[OFF_WC+(1152+h)*3+2];
  const float bdt = wsf[OFF_BC + 1152 + h] + dt_bias[h];
  const float A_h = -__expf(A_log[h]);
  const float Dh  = D_param[h];
  for (int cc = wid; cc < 64; cc += 16){
    int t = cc*64 + lane;
    const float* ob = obs + (size_t)t*(NBK*3) + b*3;
    float draw = bdt + Wd0*ob[0] + Wd1*ob[1] + Wd2*ob[2];
    float dtv = softplusf_(draw);
    float a = A_h * dtv;
    #pragma unroll
    for (int o=1;o<64;o<<=1){
      float u = __shfl_up(a, o);
      if (lane >= o) a += u;
    }
    dt_l[t] = dtv; acs_l[t] = a;
  }
  __syncthreads();

  // ---------------- prologue part 2: A-frags + OW[0] ----------------
  short8 afrag[3];
  #pragma unroll
  for (int e=0;e<3;e++){
    int idx = wid*3+e, ct = idx>>2;
    afrag[e] = *(const short8*)&W3T[(ct*16 + (lane&15))*40 + ((lane>>4)&3)*8];
  }
  if (tid < 768){
    int tt_ = tid/12, ij = tid - tt_*12;
    int i = ij/3, j = ij - i*3;
    int ts = tt_ - 3 + i;
    OW[0][tt_*40 + ij] = (ts >= 0) ? obs_b[j*4096 + ts] : (unsigned short)0;
  }
  __syncthreads();

  f32x4 sreg = {0.f,0.f,0.f,0.f};   // state tile: rows n=rbase+r, col p=bn

  for (int c = 0; c < 64; ++c){
    const int t0 = c*64;
    const float At = acs_l[t0 + 63];

    // ---------- region C: conv MFMA + epilogue + Sb + OW[c+1] ----------
    {
      // Sb[p][n] <- incoming state
      ushort4v sp;
      #pragma unroll
      for (int r=0;r<4;r++) sp[r] = f2bf(sreg[r]);
      *(ushort4v*)&Sb[SW(bn, rbase)] = sp;

      f32x4 g[3];
      #pragma unroll
      for (int e=0;e<3;e++){
        int idx = wid*3+e, tt = idx&3;
        const short8 bf = *(const short8*)&OW[c&1][(tt*16 + (lane&15))*40 + ((lane>>4)&3)*8];
        f32x4 z0 = {0.f,0.f,0.f,0.f};
        g[e] = __builtin_amdgcn_mfma_f32_16x16x32_bf16(afrag[e], bf, z0, 0, 0, 0);
      }
      #pragma unroll
      for (int e=0;e<3;e++){
        const int idx = wid*3+e, ct = idx>>2, tt = idx&3;
        const int t_  = tt*16 + (lane&15);
        const int chb = ct*16 + ((lane>>4)&3)*4;
        float dtt  = dt_l[t0 + t_];
        float acst = acs_l[t0 + t_];
        float dcy  = __expf(At - acst);
        float eAc  = __expf(acst);
        float v[4];
        #pragma unroll
        for (int r=0;r<4;r++){
          float pre = g[e][r] + CBe[chb+r];
          if (c==0 && tt==0){
            int tq = lane&15;
            if (tq < 3){
              #pragma unroll
              for (int i2=0;i2<3;i2++) if (i2 < 3-tq) pre -= TBl[(chb+r)*4+i2];
            }
          }
          v[r] = siluf_(pre);
        }
        if (ct < 4){
          int cb = chb;
          ushort4v xs_;
          #pragma unroll
          for (int r=0;r<4;r++) xs_[r] = f2bf(v[r]);
          *(ushort4v*)&XSl[SW(t_, cb)] = xs_;
          #pragma unroll
          for (int r=0;r<4;r++) XDT[SW(cb+r, t_)] = f2bf(v[r]*dtt);
        } else if (ct < 8){
          int nb = chb - 64;
          ushort4v b_;
          #pragma unroll
          for (int r=0;r<4;r++) b_[r] = f2bf(v[r]);
          *(ushort4v*)&Bs[SW(t_, nb)] = b_;
          #pragma unroll
          for (int r=0;r<4;r++) BDTl[SW(nb+r, t_)] = f2bf(v[r]*dcy);
        } else {
          int nb = chb - 128;
          ushort4v c_, ce_;
          #pragma unroll
          for (int r=0;r<4;r++){ c_[r] = f2bf(v[r]); ce_[r] = f2bf(v[r]*eAc); }
          *(ushort4v*)&Cs[SW(t_, nb)]  = c_;
          *(ushort4v*)&CEl[SW(t_, nb)] = ce_;
        }
      }
      if (c < 63 && tid < 768){
        int tt_ = tid/12, ij = tid - tt_*12;
        int i = ij/3, j = ij - i*3;
        int ts = (c+1)*64 + tt_ - 3 + i;
        OW[(c+1)&1][tt_*40 + ij] = obs_b[j*4096 + ts];
      }
    }
    __syncthreads();

    // ---------- region D: G = C·B^T, M = G ∘ L ----------
    {
      f32x4 g2 = {0.f,0.f,0.f,0.f};
      #pragma unroll
      for (int k=0;k<2;k++){
        int kb = k*32 + ((lane>>4)&3)*8;
        const short8 av = *(const short8*)&Cs[SW(am, kb)];
        const short8 bv = *(const short8*)&Bs[SW(bn, kb)];
        g2 = __builtin_amdgcn_mfma_f32_16x16x32_bf16(av, bv, g2, 0, 0, 0);
      }
      float acS = acs_l[t0 + bn];
      #pragma unroll
      for (int r=0;r<4;r++){
        int lrow = rbase + r;
        float acl = acs_l[t0 + lrow];
        float mv = (lrow >= bn) ? g2[r]*__expf(acl - acS) : 0.f;
        Mm[SW(lrow, bn)] = f2bf(mv);
      }
    }
    __syncthreads();

    // ---------- region E: Y = M·xdt^T + CE·Sb^T (+xs·D), state update ----------
    {
      f32x4 y = {0.f,0.f,0.f,0.f};
      #pragma unroll
      for (int k=0;k<2;k++){
        int kb = k*32 + ((lane>>4)&3)*8;
        const short8 av = *(const short8*)&Mm[SW(am, kb)];
        const short8 bv = *(const short8*)&XDT[SW(bn, kb)];
        y = __builtin_amdgcn_mfma_f32_16x16x32_bf16(av, bv, y, 0, 0, 0);
      }
      #pragma unroll
      for (int k=0;k<2;k++){
        int kb = k*32 + ((lane>>4)&3)*8;
        const short8 av = *(const short8*)&CEl[SW(am, kb)];
        const short8 bv = *(const short8*)&Sb[SW(bn, kb)];
        y = __builtin_amdgcn_mfma_f32_16x16x32_bf16(av, bv, y, 0, 0, 0);
      }
      float eAtot = __expf(At);
      #pragma unroll
      for (int r=0;r<4;r++) sreg[r] *= eAtot;
      #pragma unroll
      for (int k=0;k<2;k++){
        int kb = k*32 + ((lane>>4)&3)*8;
        const short8 av = *(const short8*)&BDTl[SW(am, kb)];
        const short8 bv = *(const short8*)&XDT[SW(bn, kb)];
        sreg = __builtin_amdgcn_mfma_f32_16x16x32_bf16(av, bv, sreg, 0, 0, 0);
      }
      #pragma unroll
      for (int r=0;r<4;r++){
        int lrow = rbase + r;
        float xsv = bf2f(XSl[SW(lrow, bn)]);
        Yg[((size_t)(b*4096 + t0 + lrow))*512 + h*64 + bn] = f2bf(y[r] + xsv*Dh);
      }
    }
    __syncthreads();
  }
}

// ---- final: gate with silu(z), RMSNorm, folded out-proj dot, q & logits ----
__global__ __launch_bounds__(256) void final_kernel(
    const unsigned short* __restrict__ Yg, const float* __restrict__ obs,
    const float* __restrict__ wsf, const float* __restrict__ head,
    const float* __restrict__ log_tau, float* __restrict__ out)
{
  __shared__ float Wz[512*3];
  __shared__ float bz[512];
  __shared__ float nwl[512];
  int tid = threadIdx.x;
  for (int i=tid; i<512*3; i+=256) Wz[i] = wsf[OFF_WC + i];
  for (int i=tid; i<512; i+=256){ bz[i] = wsf[OFF_BC+i]; nwl[i] = wsf[OFF_NW+i]; }
  __syncthreads();
  int wid = tid>>6, lane = tid&63;
  float hsc  = softplusf_(head[0]);
  float itau = __expf(-log_tau[0]);
  int base = blockIdx.x*64 + wid*16;
  for (int rr=0; rr<16; ++rr){
    int row = base + rr;                 // b*4096 + t
    int bb = row >> 12, t = row & 4095;
    const float* ob = obs + (size_t)t*(NBK*3) + bb*3;
    float o0=ob[0], o1=ob[1], o2=ob[2];
    ushort8 yv = *(const ushort8*)&Yg[(size_t)row*512 + lane*8];
    float s2=0.f, sq=0.f;
    #pragma unroll
    for (int u=0;u<8;u++){
      int i = lane*8+u;
      float yf = bf2f(yv[u]);
      float z = bz[i] + Wz[i*3]*o0 + Wz[i*3+1]*o1 + Wz[i*3+2]*o2;
      float yg = yf * siluf_(z);
      s2 = fmaf(yg, yg, s2);
      sq = fmaf(yg, nwl[i], sq);
    }
    #pragma unroll
    for (int o=32;o;o>>=1){ s2 += __shfl_xor(s2,o); sq += __shfl_xor(sq,o); }
    if (lane==0){
      float rms = rsqrtf(s2*(1.f/512.f) + 1e-5f);
      float q = sq * rms * hsc;
      out[(size_t)t*32 + bb] = q;
      out[131072 + (size_t)t*32 + bb] = q * itau;
    }
  }
}

extern "C" void kernel_launch(void* const* d_in, const int* in_sizes, int n_in,
                              void* d_out, int out_size, void* d_ws, size_t ws_size,
                              hipStream_t stream) {
  (void)in_sizes; (void)n_in; (void)out_size; (void)ws_size;
  const float* obs        = (const float*)d_in[0];
  const float* W_in       = (const float*)d_in[1];
  const float* b_in       = (const float*)d_in[2];
  const float* in_proj_w  = (const float*)d_in[3];
  const float* conv_w     = (const float*)d_in[4];
  const float* conv_b     = (const float*)d_in[5];
  const float* dt_bias    = (const float*)d_in[6];
  const float* A_log      = (const float*)d_in[7];
  const float* D_param    = (const float*)d_in[8];
  const float* norm_w     = (const float*)d_in[9];
  const float* out_proj_w = (const float*)d_in[10];
  const float* head       = (const float*)d_in[11];
  const float* log_tau    = (const float*)d_in[12];
  float* wsf = (float*)d_ws;
  unsigned short* Yg = (unsigned short*)((char*)d_ws + OFF_Y_BYTES);
  float* out = (float*)d_out;

  prep1_kernel<<<5, 256, 0, stream>>>(in_proj_w, W_in, b_in, wsf);
  prep2_kernel<<<3, 256, 0, stream>>>(conv_w, norm_w, out_proj_w, wsf);
  ssd_kernel<<<256, 1024, 0, stream>>>(obs, conv_b, dt_bias, A_log, D_param, wsf, Yg);
  final_kernel<<<2048, 256, 0, stream>>>(Yg, obs, wsf, head, log_tau, out);
}

// Round 3
// 391.053 us; speedup vs baseline: 1.6797x; 1.1679x over previous
//
#include <hip/hip_runtime.h>

typedef __attribute__((ext_vector_type(8))) short short8;
typedef __attribute__((ext_vector_type(4))) float f32x4;
typedef __attribute__((ext_vector_type(2))) unsigned int uint2v;

// workspace float offsets
#define OFF_WC 0        // 1160*3
#define OFF_BC 3480     // 1160
#define OFF_W3 4640     // 640*12  folded conv*proj weights
#define OFF_TB 12320    // 640*4   per-tap bias (causal pad masking)
#define OFF_NW 14880    // 512     norm_w * colsum(out_proj_w)
#define OFF_Y_BYTES 262144   // bf16 Y buffer after this byte offset

__device__ __forceinline__ unsigned short f2bf(float f){
  unsigned int u = __float_as_uint(f);
  u = (u + 0x7FFFu + ((u >> 16) & 1u)) >> 16;
  return (unsigned short)u;
}
__device__ __forceinline__ float bf2f(unsigned short h){
  return __uint_as_float(((unsigned int)h) << 16);
}
__device__ __forceinline__ unsigned int cvtpk(float lo, float hi){
  unsigned int r;
  asm("v_cvt_pk_bf16_f32 %0, %1, %2" : "=v"(r) : "v"(lo), "v"(hi));
  return r;
}
__device__ __forceinline__ float softplusf_(float x){
  return (x > 15.f) ? x : log1pf(__expf(x));
}
__device__ __forceinline__ float siluf_(float x){
  return x * __fdividef(1.f, 1.f + __expf(-x));
}

// swizzled index into a [64][64] ushort tile
#define SW(row_, col_) ((row_)*64 + ((col_) ^ (((row_)&7)<<3)))

// ---- prep 1: Wc = in_proj_w @ W_in (1160x3), biasc = in_proj_w @ b_in ----
__global__ void prep1_kernel(const float* __restrict__ ipw,
                             const float* __restrict__ W_in,
                             const float* __restrict__ b_in,
                             float* __restrict__ wsf){
  int gw = (blockIdx.x*256 + threadIdx.x) >> 6;   // wave per row
  int lane = threadIdx.x & 63;
  if (gw >= 1160) return;
  const float* row = ipw + (size_t)gw*256;
  float a0=0.f,a1=0.f,a2=0.f,ab=0.f;
  #pragma unroll
  for (int m = lane; m < 256; m += 64){
    float w = row[m];
    a0 = fmaf(w, W_in[m*3+0], a0);
    a1 = fmaf(w, W_in[m*3+1], a1);
    a2 = fmaf(w, W_in[m*3+2], a2);
    ab = fmaf(w, b_in[m], ab);
  }
  #pragma unroll
  for (int o=32;o;o>>=1){
    a0 += __shfl_xor(a0,o); a1 += __shfl_xor(a1,o);
    a2 += __shfl_xor(a2,o); ab += __shfl_xor(ab,o);
  }
  if (lane==0){
    wsf[OFF_WC + gw*3+0]=a0; wsf[OFF_WC + gw*3+1]=a1; wsf[OFF_WC + gw*3+2]=a2;
    wsf[OFF_BC + gw]=ab;
  }
}

// ---- prep 2: folded conv tables + nw = norm_w * colsum(out_proj_w) ----
__global__ void prep2_kernel(const float* __restrict__ conv_w,
                             const float* __restrict__ norm_w,
                             const float* __restrict__ out_proj_w,
                             float* __restrict__ wsf){
  int r = blockIdx.x*256 + threadIdx.x;
  if (r < 640){
    float bc = wsf[OFF_BC + 512 + r];
    #pragma unroll
    for (int i=0;i<4;i++){
      float cw = conv_w[r*4+i];
      wsf[OFF_TB + r*4+i] = cw*bc;
      wsf[OFF_W3 + r*12 + i*3+0] = cw * wsf[OFF_WC + (512+r)*3+0];
      wsf[OFF_W3 + r*12 + i*3+1] = cw * wsf[OFF_WC + (512+r)*3+1];
      wsf[OFF_W3 + r*12 + i*3+2] = cw * wsf[OFF_WC + (512+r)*3+2];
    }
  }
  if (r < 512){
    float s=0.f;
    for (int m=0;m<256;m++) s += out_proj_w[(size_t)m*512 + r];
    wsf[OFF_NW + r] = norm_w[r]*s;
  }
}

// ---- SSD: one block per (b,h); state in regs across the 64-chunk loop ----
__global__ __launch_bounds__(1024, 4) void ssd_kernel(
    const float* __restrict__ obs, const float* __restrict__ conv_b,
    const float* __restrict__ dt_bias, const float* __restrict__ A_log,
    const float* __restrict__ D_param, const float* __restrict__ wsf,
    unsigned short* __restrict__ Yg)
{
  __shared__ __align__(16) float acs_l[4096];
  __shared__ __align__(16) float dt_l[4096];
  __shared__ __align__(16) unsigned short eAc_l[4096];
  __shared__ __align__(16) unsigned short dcy_l[4096];
  __shared__ __align__(16) unsigned short BsT[2*4096];   // B   [t][n]
  __shared__ __align__(16) unsigned short CsT[2*4096];   // C   [t][n]
  __shared__ __align__(16) unsigned short CET[2*4096];   // C*eAc [t][n]
  __shared__ __align__(16) unsigned short XDTt[2*4096];  // x*dt  [p][t]
  __shared__ __align__(16) unsigned short BDTt[2*4096];  // B*dcy [n][t]
  __shared__ __align__(16) unsigned short MmSb[2*4096];  // Mm [l][s] | Sb [p][n]; W3T alias in prologue
  __shared__ __align__(16) unsigned short OW[2][64*40];  // obs window tiles (K pad 12->40)
  __shared__ float CBe[192];

  const int tid  = threadIdx.x;
  const int b    = blockIdx.x >> 3;
  const int h    = blockIdx.x & 7;
  const int lane = tid & 63;
  const int wid  = tid >> 6;          // 0..15
  const int ln15 = lane & 15;
  const int quad = (lane >> 4) & 3;
  const int quad4 = quad*4, quad8 = quad*8;
  const int tm   = wid >> 2, tn = wid & 3;
  const int am    = tm*16 + ln15;
  const int bn    = tn*16 + ln15;
  const int rbase = tm*16 + quad4;

  unsigned short* const Mm  = MmSb;
  unsigned short* const Sb  = MmSb + 4096;
  unsigned short* const W3T = MmSb;          // 192*40=7680 <= 8192, prologue only

  // ---------------- prologue: static LDS ----------------
  for (int i = tid; i < 192*40; i += 1024){
    int lc = i/40, k = i - lc*40;
    unsigned short v = 0;
    if (k < 12){
      int ch = (lc<64) ? h*64+lc : 448+lc;
      v = f2bf(wsf[OFF_W3 + ch*12 + k]);
    }
    W3T[i] = v;
  }
  for (int i = tid; i < 2*64*28; i += 1024){
    int r = i/28; (&OW[0][0])[r*40 + 12 + (i - r*28)] = 0;
  }
  if (tid < 192){
    int ch = (tid<64) ? h*64+tid : 448+tid;
    float s = conv_b[ch];
    #pragma unroll
    for (int i=0;i<4;i++) s += wsf[OFF_TB + ch*4 + i];
    CBe[tid] = s;
  }
  const float Wd0 = wsf[OFF_WC+(1152+h)*3+0], Wd1 = wsf[OFF_WC+(1152+h)*3+1],
              Wd2 = wsf[OFF_WC+(1152+h)*3+2];
  const float bdt = wsf[OFF_BC + 1152 + h] + dt_bias[h];
  const float A_h = -__expf(A_log[h]);
  const float Dh  = D_param[h];
  for (int cc = wid; cc < 64; cc += 16){
    int t = cc*64 + lane;
    const float* ob = obs + (size_t)t*96 + b*3;
    float draw = bdt + Wd0*ob[0] + Wd1*ob[1] + Wd2*ob[2];
    float dtv = softplusf_(draw);
    float a = A_h * dtv;
    #pragma unroll
    for (int o=1;o<64;o<<=1){
      float u = __shfl_up(a, o);
      if (lane >= o) a += u;
    }
    float At = __shfl(a, 63);
    dt_l[t]  = dtv;
    acs_l[t] = a;
    eAc_l[t] = f2bf(__expf(a));
    dcy_l[t] = f2bf(__expf(At - a));
  }
  __syncthreads();

  // hoist W3 fragments + channel biases into registers
  short8 afrag1[2], afrag2[2];
  float  cbe1[2][4], cbe2[2];
  #pragma unroll
  for (int e=0;e<2;e++){
    const int idx = wid*2+e;
    const int ct1 = 4 + (idx & 7);
    afrag1[e] = *(const short8*)&W3T[(ct1*16 + ln15)*40 + quad8];
    #pragma unroll
    for (int r=0;r<4;r++) cbe1[e][r] = CBe[ct1*16 + quad4 + r];
    const int ct2 = idx & 7;
    afrag2[e] = *(const short8*)&W3T[(ct2*16 + ln15)*40 + quad8];
    cbe2[e] = CBe[ct2*16 + ln15];
  }

  auto PREFOW = [&](int cn){
    if (tid < 768){
      int tt_ = tid/12, ij = tid - tt_*12;
      int i = ij/3, j = ij - i*3;
      int ts = cn*64 + tt_ - 3 + i;
      OW[cn&1][tt_*40 + ij] = (ts >= 0) ? f2bf(obs[(size_t)ts*96 + b*3 + j])
                                        : (unsigned short)0;
    }
  };
  PREFOW(0);
  PREFOW(1);
  __syncthreads();

  auto STAGE = [&](int cn, int pn){
    unsigned short* Bp  = BsT  + pn*4096;
    unsigned short* Cp  = CsT  + pn*4096;
    unsigned short* CEp = CET  + pn*4096;
    unsigned short* Xp  = XDTt + pn*4096;
    unsigned short* BDp = BDTt + pn*4096;
    const int tW0 = cn*64;
    #pragma unroll
    for (int e=0;e<2;e++){
      const int idx = wid*2+e;
      const int tt  = idx >> 3;
      const short8 owf = *(const short8*)&OW[cn&1][(tt*16 + ln15)*40 + quad8];
      // ---- o1: D[ch][t] -> Bs / Cs / CEl ([t][n] tiles) ----
      {
        const int ct1 = 4 + (idx & 7);
        const int chb = ct1*16 + quad4;    // local ch 64..188
        const int t_  = tt*16 + ln15;
        f32x4 z0 = {0.f,0.f,0.f,0.f};
        f32x4 g = __builtin_amdgcn_mfma_f32_16x16x32_bf16(afrag1[e], owf, z0, 0,0,0);
        float v[4];
        #pragma unroll
        for (int r=0;r<4;r++){
          float pre = g[r] + cbe1[e][r];
          if (cn==0 && tt==0 && ln15 < 3){
            int chg = 448 + chb + r;
            #pragma unroll
            for (int i2=0;i2<3;i2++) if (i2 < 3-ln15) pre -= wsf[OFF_TB + chg*4 + i2];
          }
          v[r] = siluf_(pre);
        }
        if (ct1 < 8){
          int nb = chb - 64;
          *(uint2v*)&Bp[SW(t_, nb)] = (uint2v){cvtpk(v[0],v[1]), cvtpk(v[2],v[3])};
        } else {
          int nb = chb - 128;
          *(uint2v*)&Cp[SW(t_, nb)] = (uint2v){cvtpk(v[0],v[1]), cvtpk(v[2],v[3])};
          float ea = bf2f(eAc_l[tW0 + t_]);
          *(uint2v*)&CEp[SW(t_, nb)] =
            (uint2v){cvtpk(v[0]*ea, v[1]*ea), cvtpk(v[2]*ea, v[3]*ea)};
        }
      }
      // ---- o2: D[t][ch] -> XDT / BDT ([p|n][t] tiles) ----
      {
        const int ct2 = idx & 7;
        const int ch2 = ct2*16 + ln15;     // local ch 0..127
        const int tb2 = tt*16 + quad4;
        f32x4 z0 = {0.f,0.f,0.f,0.f};
        f32x4 g = __builtin_amdgcn_mfma_f32_16x16x32_bf16(owf, afrag2[e], z0, 0,0,0);
        float v[4];
        #pragma unroll
        for (int r=0;r<4;r++){
          float pre = g[r] + cbe2[e];
          if (cn==0 && tt==0 && quad==0 && r<3){
            int chg = (ch2<64) ? h*64+ch2 : 448+ch2;
            #pragma unroll
            for (int i2=0;i2<3;i2++) if (i2 < 3-r) pre -= wsf[OFF_TB + chg*4 + i2];
          }
          v[r] = siluf_(pre);
        }
        if (ct2 < 4){
          float m0 = v[0]*dt_l[tW0+tb2+0], m1 = v[1]*dt_l[tW0+tb2+1];
          float m2 = v[2]*dt_l[tW0+tb2+2], m3 = v[3]*dt_l[tW0+tb2+3];
          *(uint2v*)&Xp[SW(ch2, tb2)] = (uint2v){cvtpk(m0,m1), cvtpk(m2,m3)};
        } else {
          int nb = ch2 - 64;
          float m0 = v[0]*bf2f(dcy_l[tW0+tb2+0]), m1 = v[1]*bf2f(dcy_l[tW0+tb2+1]);
          float m2 = v[2]*bf2f(dcy_l[tW0+tb2+2]), m3 = v[3]*bf2f(dcy_l[tW0+tb2+3]);
          *(uint2v*)&BDp[SW(nb, tb2)] = (uint2v){cvtpk(m0,m1), cvtpk(m2,m3)};
        }
      }
    }
  };

  STAGE(0, 0);
  __syncthreads();

  f32x4 sreg = {0.f,0.f,0.f,0.f};   // state S[n][p]: rows n=rbase+r, col p=bn

  for (int c = 0; c < 64; ++c){
    const int t0 = c*64;
    const int p  = c & 1;
    const unsigned short* Bp  = BsT  + p*4096;
    const unsigned short* Cp  = CsT  + p*4096;
    const unsigned short* CEp = CET  + p*4096;
    const unsigned short* Xp  = XDTt + p*4096;
    const unsigned short* BDp = BDTt + p*4096;

    // ---------- R1: Sb write, stage(c+1), prefetch OW(c+2), D(c) ----------
    *(uint2v*)&Sb[SW(bn, rbase)] = (uint2v){cvtpk(sreg[0],sreg[1]), cvtpk(sreg[2],sreg[3])};
    if (c < 63) STAGE(c+1, (c+1)&1);
    if (c < 62) PREFOW(c+2);
    {
      // G^T[s][l] = sum_n B[s,n]*C[l,n]; M[l][s] written as b64 rows
      f32x4 g2 = {0.f,0.f,0.f,0.f};
      #pragma unroll
      for (int k=0;k<2;k++){
        int kb = k*32 + quad8;
        const short8 av = *(const short8*)&Bp[SW(am, kb)];
        const short8 bv = *(const short8*)&Cp[SW(bn, kb)];
        g2 = __builtin_amdgcn_mfma_f32_16x16x32_bf16(av, bv, g2, 0, 0, 0);
      }
      float acB  = acs_l[t0 + bn];
      float diag = __fdividef(Dh, dt_l[t0 + bn]);
      float mv[4];
      #pragma unroll
      for (int r=0;r<4;r++){
        int srow = rbase + r;
        float m_ = (bn >= srow) ? g2[r]*__expf(acB - acs_l[t0 + srow]) : 0.f;
        if (bn == srow) m_ += diag;
        mv[r] = m_;
      }
      *(uint2v*)&Mm[SW(bn, rbase)] = (uint2v){cvtpk(mv[0],mv[1]), cvtpk(mv[2],mv[3])};
    }
    __syncthreads();

    // ---------- R2: E(c): Y = M*xdt + CE*S (+diag-folded), state update ----------
    {
      short8 xf[2];
      #pragma unroll
      for (int k=0;k<2;k++) xf[k] = *(const short8*)&Xp[SW(bn, k*32 + quad8)];
      f32x4 y = {0.f,0.f,0.f,0.f};
      #pragma unroll
      for (int k=0;k<2;k++){
        int kb = k*32 + quad8;
        const short8 av = *(const short8*)&Mm[SW(am, kb)];
        y = __builtin_amdgcn_mfma_f32_16x16x32_bf16(av, xf[k], y, 0, 0, 0);
      }
      #pragma unroll
      for (int k=0;k<2;k++){
        int kb = k*32 + quad8;
        const short8 av = *(const short8*)&CEp[SW(am, kb)];
        const short8 bv = *(const short8*)&Sb[SW(bn, kb)];
        y = __builtin_amdgcn_mfma_f32_16x16x32_bf16(av, bv, y, 0, 0, 0);
      }
      float eAtot = __expf(acs_l[t0 + 63]);
      #pragma unroll
      for (int r=0;r<4;r++) sreg[r] *= eAtot;
      #pragma unroll
      for (int k=0;k<2;k++){
        int kb = k*32 + quad8;
        const short8 av = *(const short8*)&BDp[SW(am, kb)];
        sreg = __builtin_amdgcn_mfma_f32_16x16x32_bf16(av, xf[k], sreg, 0, 0, 0);
      }
      #pragma unroll
      for (int r=0;r<4;r++){
        Yg[((size_t)(b*4096 + t0 + rbase + r))*512 + h*64 + bn] = f2bf(y[r]);
      }
    }
    __syncthreads();
  }
}

// ---- final: gate with silu(z), RMSNorm, folded out-proj dot, q & logits ----
__global__ __launch_bounds__(256) void final_kernel(
    const unsigned short* __restrict__ Yg, const float* __restrict__ obs,
    const float* __restrict__ wsf, const float* __restrict__ head,
    const float* __restrict__ log_tau, float* __restrict__ out)
{
  int tid = threadIdx.x;
  int wv = tid >> 6, lane = tid & 63;
  // per-thread channels ch = u*64 + lane: weights in registers, no LDS
  float zw0[8], zw1[8], zw2[8], zb[8], znw[8];
  #pragma unroll
  for (int u=0;u<8;u++){
    int ch = u*64 + lane;
    zw0[u] = wsf[OFF_WC + ch*3+0];
    zw1[u] = wsf[OFF_WC + ch*3+1];
    zw2[u] = wsf[OFF_WC + ch*3+2];
    zb[u]  = wsf[OFF_BC + ch];
    znw[u] = wsf[OFF_NW + ch];
  }
  float hsc  = softplusf_(head[0]);
  float itau = __expf(-log_tau[0]);
  int base = blockIdx.x*64 + wv*16;
  for (int rr=0; rr<16; ++rr){
    int row = base + rr;               // b*4096 + t
    int bb = row >> 12, t = row & 4095;
    const float* ob = obs + (size_t)t*96 + bb*3;
    float o0=ob[0], o1=ob[1], o2=ob[2];
    float s2=0.f, sq=0.f;
    #pragma unroll
    for (int u=0;u<8;u++){
      float yf = bf2f(Yg[(size_t)row*512 + u*64 + lane]);
      float z  = zb[u] + zw0[u]*o0 + zw1[u]*o1 + zw2[u]*o2;
      float yg = yf * siluf_(z);
      s2 = fmaf(yg, yg, s2);
      sq = fmaf(yg, znw[u], sq);
    }
    #pragma unroll
    for (int o=32;o;o>>=1){ s2 += __shfl_xor(s2,o); sq += __shfl_xor(sq,o); }
    if (lane==0){
      float rms = rsqrtf(s2*(1.f/512.f) + 1e-5f);
      float q = sq * rms * hsc;
      out[(size_t)t*32 + bb] = q;
      out[131072 + (size_t)t*32 + bb] = q * itau;
    }
  }
}

extern "C" void kernel_launch(void* const* d_in, const int* in_sizes, int n_in,
                              void* d_out, int out_size, void* d_ws, size_t ws_size,
                              hipStream_t stream) {
  (void)in_sizes; (void)n_in; (void)out_size; (void)ws_size;
  const float* obs        = (const float*)d_in[0];
  const float* W_in       = (const float*)d_in[1];
  const float* b_in       = (const float*)d_in[2];
  const float* in_proj_w  = (const float*)d_in[3];
  const float* conv_w     = (const float*)d_in[4];
  const float* conv_b     = (const float*)d_in[5];
  const float* dt_bias    = (const float*)d_in[6];
  const float* A_log      = (const float*)d_in[7];
  const float* D_param    = (const float*)d_in[8];
  const float* norm_w     = (const float*)d_in[9];
  const float* out_proj_w = (const float*)d_in[10];
  const float* head       = (const float*)d_in[11];
  const float* log_tau    = (const float*)d_in[12];
  float* wsf = (float*)d_ws;
  unsigned short* Yg = (unsigned short*)((char*)d_ws + OFF_Y_BYTES);
  float* out = (float*)d_out;

  prep1_kernel<<<290, 256, 0, stream>>>(in_proj_w, W_in, b_in, wsf);
  prep2_kernel<<<3, 256, 0, stream>>>(conv_w, norm_w, out_proj_w, wsf);
  ssd_kernel<<<256, 1024, 0, stream>>>(obs, conv_b, dt_bias, A_log, D_param, wsf, Yg);
  final_kernel<<<2048, 256, 0, stream>>>(Yg, obs, wsf, head, log_tau, out);
}